// Round 1
// baseline (676.688 us; speedup 1.0000x reference)
//
#include <hip/hip_runtime.h>

#define TDIM 512  // T, fixed by the problem (in_sizes[0]/in_sizes[1] == 512)

__global__ __launch_bounds__(256) void surv_loss_kernel(
    const float* __restrict__ y_pred,
    const int* __restrict__ y,
    const int* __restrict__ status,
    float* __restrict__ out,
    unsigned char* __restrict__ ws,
    int nrows) {
  double* acc = reinterpret_cast<double*>(ws);
  unsigned int* counter = reinterpret_cast<unsigned int*>(ws + 8);

  const int lane = threadIdx.x & 63;
  const int widb = threadIdx.x >> 6;          // wave id in block (0..3)
  const int gwave = blockIdx.x * 4 + widb;    // global wave id
  const int nwaves = gridDim.x * 4;

  float wacc = 0.0f;  // only lane 0 of each wave accumulates into this

  for (int row = gwave; row < nrows; row += nwaves) {
    const int v = y[row];
    const int st = status[row];
    const float* rowp = y_pred + (size_t)row * TDIM;

    if (st == 1) {
      // -log(y_pred[row, v]) — single element
      if (lane == 0) wacc -= logf(rowp[v]);
    } else {
      // -log(1 - sum_{j<v} y_pred[row, j]) — exclusive prefix sum
      float s = 0.0f;
      // pass 0: elements [0, 256); lane covers [4*lane, 4*lane+4)
      {
        const int e0 = lane * 4;
        if (e0 < v) {
          float4 d = *reinterpret_cast<const float4*>(rowp + e0);
          s += d.x;
          if (e0 + 1 < v) s += d.y;
          if (e0 + 2 < v) s += d.z;
          if (e0 + 3 < v) s += d.w;
        }
      }
      // pass 1: elements [256, 512)
      {
        const int e1 = 256 + lane * 4;
        if (e1 < v) {
          float4 d = *reinterpret_cast<const float4*>(rowp + e1);
          s += d.x;
          if (e1 + 1 < v) s += d.y;
          if (e1 + 2 < v) s += d.z;
          if (e1 + 3 < v) s += d.w;
        }
      }
      // 64-lane butterfly reduce
      #pragma unroll
      for (int off = 32; off >= 1; off >>= 1) s += __shfl_xor(s, off, 64);
      if (lane == 0) wacc -= logf(1.0f - s);
    }
  }

  // block reduce (4 waves)
  __shared__ float sm[4];
  if (lane == 0) sm[widb] = wacc;
  __syncthreads();
  if (threadIdx.x == 0) {
    float bsum = sm[0] + sm[1] + sm[2] + sm[3];
    atomicAdd(acc, (double)bsum);
    __threadfence();
    unsigned int old = atomicAdd(counter, 1u);
    if (old == gridDim.x - 1) {
      __threadfence();
      double total = atomicAdd(acc, 0.0);  // coherent L2 read of final sum
      out[0] = (float)total;
    }
  }
}

extern "C" void kernel_launch(void* const* d_in, const int* in_sizes, int n_in,
                              void* d_out, int out_size, void* d_ws, size_t ws_size,
                              hipStream_t stream) {
  const float* y_pred = (const float*)d_in[0];
  const int* y = (const int*)d_in[1];
  const int* status = (const int*)d_in[2];
  float* out = (float*)d_out;
  const int nrows = in_sizes[1];  // B = 262144

  // zero the double accumulator + finish counter (ws is re-poisoned 0xAA each call)
  hipMemsetAsync(d_ws, 0, 16, stream);

  const int grid = 2048;  // 8192 waves, 32 rows/wave, 32 waves/CU
  surv_loss_kernel<<<grid, 256, 0, stream>>>(y_pred, y, status, out,
                                             (unsigned char*)d_ws, nrows);
}